// Round 1
// baseline (759.729 us; speedup 1.0000x reference)
//
#include <hip/hip_runtime.h>

#define NEGF (-1e30f)

namespace {

constexpr int B = 4, T = 512, L = 64, U = 65, V = 1024;

__device__ __forceinline__ float lse2(float a, float b) {
    // logaddexp; safe when one/both operands are ~-1e30 (exp underflows to 0)
    float m = fmaxf(a, b);
    float d = fminf(a, b) - m;
    return m + __logf(1.0f + __expf(d));
}

// ---------------------------------------------------------------------------
// Kernel 1: per-(b,t,u) log-softmax terms.
// One wave per row of V=1024 floats: 16 floats/lane via 4x float4 (coalesced
// 1 KiB/instr). Writes lp_blank and lp_label into d_ws in [B][U][T] layout
// (transposed) so the DP kernel reads per-lane contiguous float4 in t.
// lp_label is stored SHIFTED: slot u holds log P(emit targets[u-1]) so DP
// lane u reads its own row (row u=0 unused).
// ---------------------------------------------------------------------------
__global__ __launch_bounds__(256) void rna_lse_kernel(
    const float* __restrict__ logits, const int* __restrict__ targets,
    float* __restrict__ lpb, float* __restrict__ lpl) {
    const int lane = threadIdx.x & 63;
    const int row  = blockIdx.x * 4 + (threadIdx.x >> 6);   // (b,t,u) flat
    const int u  = row % U;
    const int bt = row / U;
    const int t  = bt % T;
    const int b  = bt / T;

    const float*  p  = logits + (size_t)row * V;
    const float4* p4 = (const float4*)p;
    float4 v0 = p4[lane];
    float4 v1 = p4[lane + 64];
    float4 v2 = p4[lane + 128];
    float4 v3 = p4[lane + 192];

    float m = fmaxf(fmaxf(fmaxf(v0.x, v0.y), fmaxf(v0.z, v0.w)),
              fmaxf(fmaxf(fmaxf(v1.x, v1.y), fmaxf(v1.z, v1.w)),
              fmaxf(fmaxf(fmaxf(v2.x, v2.y), fmaxf(v2.z, v2.w)),
                    fmaxf(fmaxf(v3.x, v3.y), fmaxf(v3.z, v3.w)))));
#pragma unroll
    for (int off = 32; off > 0; off >>= 1)
        m = fmaxf(m, __shfl_xor(m, off, 64));

    float s = __expf(v0.x - m) + __expf(v0.y - m) + __expf(v0.z - m) + __expf(v0.w - m)
            + __expf(v1.x - m) + __expf(v1.y - m) + __expf(v1.z - m) + __expf(v1.w - m)
            + __expf(v2.x - m) + __expf(v2.y - m) + __expf(v2.z - m) + __expf(v2.w - m)
            + __expf(v3.x - m) + __expf(v3.y - m) + __expf(v3.z - m) + __expf(v3.w - m);
#pragma unroll
    for (int off = 32; off > 0; off >>= 1)
        s += __shfl_xor(s, off, 64);

    if (lane == 0) {
        float lse = m + __logf(s);
        // blank token == element 0 == lane 0's v0.x
        lpb[(b * U + u) * T + t] = v0.x - lse;
        if (u < L) {
            int tgt = targets[b * L + u];
            lpl[(b * U + u + 1) * T + t] = p[tgt] - lse;   // L1-warm reload
        }
    }
}

// ---------------------------------------------------------------------------
// Kernel 2: forward lattice DP. One block, wave w = batch w.
// Lane u holds alpha[u] in a register; alpha[u-1] via shuffle-up; state 64
// rides on lane 63 (second register). Groups of 8 timesteps, one-group-ahead
// prefetch (2x float4 per stream) to hide L2/L3 latency. No barriers in loop.
// ---------------------------------------------------------------------------
__global__ __launch_bounds__(256) void rna_dp_kernel(
    const float* __restrict__ lpb, const float* __restrict__ lpl,
    const int* __restrict__ fbank_len, const int* __restrict__ text_len,
    float* __restrict__ out) {
    __shared__ float res[B];
    const int lane = threadIdx.x & 63;
    const int b    = threadIdx.x >> 6;
    const int fb   = fbank_len[b];
    const int tl   = text_len[b];

    const float* pbR   = lpb + (b * U + lane) * T;
    const float* plR   = lpl + (b * U + lane) * T;   // shifted label lp (row 0 garbage, unused)
    const float* pbR64 = lpb + (b * U + 64) * T;     // wave-uniform -> broadcast load
    const float* plR64 = lpl + (b * U + 64) * T;

    float alpha   = (lane == 0) ? 0.0f : NEGF;
    float alpha64 = NEGF;                            // only lane 63's copy is meaningful

    float cb[8], cl[8], cb64[8], cl64[8];
    {
        float4 a0 = *(const float4*)(pbR);     float4 a1 = *(const float4*)(pbR + 4);
        cb[0]=a0.x; cb[1]=a0.y; cb[2]=a0.z; cb[3]=a0.w;
        cb[4]=a1.x; cb[5]=a1.y; cb[6]=a1.z; cb[7]=a1.w;
        float4 b0 = *(const float4*)(plR);     float4 b1 = *(const float4*)(plR + 4);
        cl[0]=b0.x; cl[1]=b0.y; cl[2]=b0.z; cl[3]=b0.w;
        cl[4]=b1.x; cl[5]=b1.y; cl[6]=b1.z; cl[7]=b1.w;
        float4 c0 = *(const float4*)(pbR64);   float4 c1 = *(const float4*)(pbR64 + 4);
        cb64[0]=c0.x; cb64[1]=c0.y; cb64[2]=c0.z; cb64[3]=c0.w;
        cb64[4]=c1.x; cb64[5]=c1.y; cb64[6]=c1.z; cb64[7]=c1.w;
        float4 d0 = *(const float4*)(plR64);   float4 d1 = *(const float4*)(plR64 + 4);
        cl64[0]=d0.x; cl64[1]=d0.y; cl64[2]=d0.z; cl64[3]=d0.w;
        cl64[4]=d1.x; cl64[5]=d1.y; cl64[6]=d1.z; cl64[7]=d1.w;
    }

    for (int t0 = 0; t0 < fb; t0 += 8) {
        float nb[8], nl[8], nb64[8], nl64[8];
        const bool pf = (t0 + 8 < fb);
        if (pf) {
            const int tn = t0 + 8;
            float4 a0 = *(const float4*)(pbR + tn);   float4 a1 = *(const float4*)(pbR + tn + 4);
            nb[0]=a0.x; nb[1]=a0.y; nb[2]=a0.z; nb[3]=a0.w;
            nb[4]=a1.x; nb[5]=a1.y; nb[6]=a1.z; nb[7]=a1.w;
            float4 b0 = *(const float4*)(plR + tn);   float4 b1 = *(const float4*)(plR + tn + 4);
            nl[0]=b0.x; nl[1]=b0.y; nl[2]=b0.z; nl[3]=b0.w;
            nl[4]=b1.x; nl[5]=b1.y; nl[6]=b1.z; nl[7]=b1.w;
            float4 c0 = *(const float4*)(pbR64 + tn); float4 c1 = *(const float4*)(pbR64 + tn + 4);
            nb64[0]=c0.x; nb64[1]=c0.y; nb64[2]=c0.z; nb64[3]=c0.w;
            nb64[4]=c1.x; nb64[5]=c1.y; nb64[6]=c1.z; nb64[7]=c1.w;
            float4 d0 = *(const float4*)(plR64 + tn); float4 d1 = *(const float4*)(plR64 + tn + 4);
            nl64[0]=d0.x; nl64[1]=d0.y; nl64[2]=d0.z; nl64[3]=d0.w;
            nl64[4]=d1.x; nl64[5]=d1.y; nl64[6]=d1.z; nl64[7]=d1.w;
        }
#pragma unroll
        for (int j = 0; j < 8; ++j) {
            if (t0 + j >= fb) break;
            float ap   = __shfl_up(alpha, 1, 64);
            float stay = alpha + cb[j];
            float move = (lane == 0) ? NEGF : (ap + cl[j]);
            float na   = lse2(stay, move);
            // state 64: uses OLD alpha[63] (lane-local, still pre-update).
            // Computed on all lanes (uniform loads); only lane 63's value is real.
            float stay64 = alpha64 + cb64[j];
            float move64 = alpha + cl64[j];
            alpha64 = lse2(stay64, move64);
            alpha   = na;
        }
        if (pf) {
#pragma unroll
            for (int j = 0; j < 8; ++j) {
                cb[j] = nb[j]; cl[j] = nl[j]; cb64[j] = nb64[j]; cl64[j] = nl64[j];
            }
        }
    }

    float ans = (tl < 64) ? __shfl(alpha, tl, 64) : __shfl(alpha64, 63, 64);
    if (lane == 0) res[b] = ans;
    __syncthreads();
    if (threadIdx.x == 0)
        out[0] = -(res[0] + res[1] + res[2] + res[3]) * (1.0f / B);
}

} // namespace

extern "C" void kernel_launch(void* const* d_in, const int* in_sizes, int n_in,
                              void* d_out, int out_size, void* d_ws, size_t ws_size,
                              hipStream_t stream) {
    const float* logits  = (const float*)d_in[0];
    const int*   targets = (const int*)d_in[1];
    const int*   fbl     = (const int*)d_in[2];
    const int*   txl     = (const int*)d_in[3];
    float* lpb = (float*)d_ws;                 // [B][U][T]
    float* lpl = lpb + (size_t)B * U * T;      // [B][U][T], slot u holds label lp for move into u
    float* out = (float*)d_out;

    const int rows = B * T * U;                // 133,120 = 33,280 blocks * 4 waves
    rna_lse_kernel<<<rows / 4, 256, 0, stream>>>(logits, targets, lpb, lpl);
    rna_dp_kernel<<<1, 256, 0, stream>>>(lpb, lpl, fbl, txl, out);
}

// Round 2
// 720.174 us; speedup vs baseline: 1.0549x; 1.0549x over previous
//
#include <hip/hip_runtime.h>

#define NEGF (-1e30f)

namespace {

constexpr int B = 4, T = 512, L = 64, U = 65, V = 1024;

__device__ __forceinline__ float lse2(float a, float b) {
    // logaddexp; safe when one/both operands are ~-1e30 (exp underflows to 0)
    float m = fmaxf(a, b);
    float d = fminf(a, b) - m;
    return m + __logf(1.0f + __expf(d));
}

// ---------------------------------------------------------------------------
// Kernel 1: per-(b,t,u) log-softmax terms.
// One wave per row of V=1024 floats: 16 floats/lane via 4x float4 (coalesced
// 1 KiB/instr). Writes lp_blank and lp_label into d_ws in [B][U][T] layout
// (transposed) so the DP kernel reads per-lane contiguous float4 in t.
// lp_label is stored SHIFTED: slot u holds log P(emit targets[u-1]) so DP
// lane u reads its own row (row u=0 unused).
//
// TRAPEZOID SKIP: the final answer alpha[fb][tl] only depends on cells with
//   t < fb, u <= tl, u <= t+1 (diagonal reachability), tl-u <= fb-t
// (can still reach tl). Waves outside early-exit BEFORE loading -> real HBM
// savings (~40% of 545 MB). Skipped slots keep 0xAA poison; DP proof: poison
// never flows into the needed region (lane info flows u-1 -> u only; the
// diagonal is additionally clamped in the DP kernel).
// ---------------------------------------------------------------------------
__global__ __launch_bounds__(256) void rna_lse_kernel(
    const float* __restrict__ logits, const int* __restrict__ targets,
    const int* __restrict__ fbank_len, const int* __restrict__ text_len,
    float* __restrict__ lpb, float* __restrict__ lpl) {
    const int lane = threadIdx.x & 63;
    const int row  = blockIdx.x * 4 + (threadIdx.x >> 6);   // (b,t,u) flat
    const int u  = row % U;
    const int bt = row / U;
    const int t  = bt % T;
    const int b  = bt / T;

    // wave-uniform early exit (b,t,u are uniform per wave -> scalar branch)
    const int fb = fbank_len[b];
    const int tl = text_len[b];
    if (t >= fb || u > tl || u > t + 1 || (tl - u) > (fb - t)) return;

    const float*  p  = logits + (size_t)row * V;
    const float4* p4 = (const float4*)p;
    float4 v0 = p4[lane];
    float4 v1 = p4[lane + 64];
    float4 v2 = p4[lane + 128];
    float4 v3 = p4[lane + 192];

    float m = fmaxf(fmaxf(fmaxf(v0.x, v0.y), fmaxf(v0.z, v0.w)),
              fmaxf(fmaxf(fmaxf(v1.x, v1.y), fmaxf(v1.z, v1.w)),
              fmaxf(fmaxf(fmaxf(v2.x, v2.y), fmaxf(v2.z, v2.w)),
                    fmaxf(fmaxf(v3.x, v3.y), fmaxf(v3.z, v3.w)))));
#pragma unroll
    for (int off = 32; off > 0; off >>= 1)
        m = fmaxf(m, __shfl_xor(m, off, 64));

    float s = __expf(v0.x - m) + __expf(v0.y - m) + __expf(v0.z - m) + __expf(v0.w - m)
            + __expf(v1.x - m) + __expf(v1.y - m) + __expf(v1.z - m) + __expf(v1.w - m)
            + __expf(v2.x - m) + __expf(v2.y - m) + __expf(v2.z - m) + __expf(v2.w - m)
            + __expf(v3.x - m) + __expf(v3.y - m) + __expf(v3.z - m) + __expf(v3.w - m);
#pragma unroll
    for (int off = 32; off > 0; off >>= 1)
        s += __shfl_xor(s, off, 64);

    if (lane == 0) {
        float lse = m + __logf(s);
        // blank token == element 0 == lane 0's v0.x
        lpb[(b * U + u) * T + t] = v0.x - lse;
        if (u < L) {
            int tgt = targets[b * L + u];
            lpl[(b * U + u + 1) * T + t] = p[tgt] - lse;   // L1-warm reload
        }
    }
}

// ---------------------------------------------------------------------------
// Kernel 2: forward lattice DP. One block, wave w = batch w.
// Lane u holds alpha[u] in a register; alpha[u-1] via shuffle-up; state 64
// rides on lane 63 (second register). Groups of 8 timesteps, one-group-ahead
// prefetch (2x float4 per stream) to hide L2/L3 latency. No barriers in loop.
// Diagonal clamp (lane > t+1 -> NEG) keeps the trapezoid-skipped poison
// region from ever contaminating needed lanes, even if poison were NaN.
// ---------------------------------------------------------------------------
__global__ __launch_bounds__(256) void rna_dp_kernel(
    const float* __restrict__ lpb, const float* __restrict__ lpl,
    const int* __restrict__ fbank_len, const int* __restrict__ text_len,
    float* __restrict__ out) {
    __shared__ float res[B];
    const int lane = threadIdx.x & 63;
    const int b    = threadIdx.x >> 6;
    const int fb   = fbank_len[b];
    const int tl   = text_len[b];

    const float* pbR   = lpb + (b * U + lane) * T;
    const float* plR   = lpl + (b * U + lane) * T;   // shifted label lp (row 0 garbage, unused)
    const float* pbR64 = lpb + (b * U + 64) * T;     // wave-uniform -> broadcast load
    const float* plR64 = lpl + (b * U + 64) * T;

    float alpha   = (lane == 0) ? 0.0f : NEGF;
    float alpha64 = NEGF;                            // only lane 63's copy is meaningful

    float cb[8], cl[8], cb64[8], cl64[8];
    {
        float4 a0 = *(const float4*)(pbR);     float4 a1 = *(const float4*)(pbR + 4);
        cb[0]=a0.x; cb[1]=a0.y; cb[2]=a0.z; cb[3]=a0.w;
        cb[4]=a1.x; cb[5]=a1.y; cb[6]=a1.z; cb[7]=a1.w;
        float4 b0 = *(const float4*)(plR);     float4 b1 = *(const float4*)(plR + 4);
        cl[0]=b0.x; cl[1]=b0.y; cl[2]=b0.z; cl[3]=b0.w;
        cl[4]=b1.x; cl[5]=b1.y; cl[6]=b1.z; cl[7]=b1.w;
        float4 c0 = *(const float4*)(pbR64);   float4 c1 = *(const float4*)(pbR64 + 4);
        cb64[0]=c0.x; cb64[1]=c0.y; cb64[2]=c0.z; cb64[3]=c0.w;
        cb64[4]=c1.x; cb64[5]=c1.y; cb64[6]=c1.z; cb64[7]=c1.w;
        float4 d0 = *(const float4*)(plR64);   float4 d1 = *(const float4*)(plR64 + 4);
        cl64[0]=d0.x; cl64[1]=d0.y; cl64[2]=d0.z; cl64[3]=d0.w;
        cl64[4]=d1.x; cl64[5]=d1.y; cl64[6]=d1.z; cl64[7]=d1.w;
    }

    for (int t0 = 0; t0 < fb; t0 += 8) {
        float nb[8], nl[8], nb64[8], nl64[8];
        const bool pf = (t0 + 8 < fb);
        if (pf) {
            const int tn = t0 + 8;
            float4 a0 = *(const float4*)(pbR + tn);   float4 a1 = *(const float4*)(pbR + tn + 4);
            nb[0]=a0.x; nb[1]=a0.y; nb[2]=a0.z; nb[3]=a0.w;
            nb[4]=a1.x; nb[5]=a1.y; nb[6]=a1.z; nb[7]=a1.w;
            float4 b0 = *(const float4*)(plR + tn);   float4 b1 = *(const float4*)(plR + tn + 4);
            nl[0]=b0.x; nl[1]=b0.y; nl[2]=b0.z; nl[3]=b0.w;
            nl[4]=b1.x; nl[5]=b1.y; nl[6]=b1.z; nl[7]=b1.w;
            float4 c0 = *(const float4*)(pbR64 + tn); float4 c1 = *(const float4*)(pbR64 + tn + 4);
            nb64[0]=c0.x; nb64[1]=c0.y; nb64[2]=c0.z; nb64[3]=c0.w;
            nb64[4]=c1.x; nb64[5]=c1.y; nb64[6]=c1.z; nb64[7]=c1.w;
            float4 d0 = *(const float4*)(plR64 + tn); float4 d1 = *(const float4*)(plR64 + tn + 4);
            nl64[0]=d0.x; nl64[1]=d0.y; nl64[2]=d0.z; nl64[3]=d0.w;
            nl64[4]=d1.x; nl64[5]=d1.y; nl64[6]=d1.z; nl64[7]=d1.w;
        }
#pragma unroll
        for (int j = 0; j < 8; ++j) {
            if (t0 + j >= fb) break;
            const int t = t0 + j;
            float ap   = __shfl_up(alpha, 1, 64);
            float stay = alpha + cb[j];
            float move = (lane == 0) ? NEGF : (ap + cl[j]);
            float na   = lse2(stay, move);
            // state 64: uses OLD alpha[63] (lane-local, still pre-update).
            float stay64 = alpha64 + cb64[j];
            float move64 = alpha + cl64[j];
            alpha64 = lse2(stay64, move64);
            alpha   = na;
            // diagonal clamp: alpha^{t+1}[u] is -inf for u > t+1; kills any
            // poison from trapezoid-skipped LSE rows.
            if (lane > t + 1) alpha = NEGF;
            if (t + 1 < 64)   alpha64 = NEGF;
        }
        if (pf) {
#pragma unroll
            for (int j = 0; j < 8; ++j) {
                cb[j] = nb[j]; cl[j] = nl[j]; cb64[j] = nb64[j]; cl64[j] = nl64[j];
            }
        }
    }

    float ans = (tl < 64) ? __shfl(alpha, tl, 64) : __shfl(alpha64, 63, 64);
    if (lane == 0) res[b] = ans;
    __syncthreads();
    if (threadIdx.x == 0)
        out[0] = -(res[0] + res[1] + res[2] + res[3]) * (1.0f / B);
}

} // namespace

extern "C" void kernel_launch(void* const* d_in, const int* in_sizes, int n_in,
                              void* d_out, int out_size, void* d_ws, size_t ws_size,
                              hipStream_t stream) {
    const float* logits  = (const float*)d_in[0];
    const int*   targets = (const int*)d_in[1];
    const int*   fbl     = (const int*)d_in[2];
    const int*   txl     = (const int*)d_in[3];
    float* lpb = (float*)d_ws;                 // [B][U][T]
    float* lpl = lpb + (size_t)B * U * T;      // [B][U][T], slot u holds label lp for move into u
    float* out = (float*)d_out;

    const int rows = B * T * U;                // 133,120 = 33,280 blocks * 4 waves
    rna_lse_kernel<<<rows / 4, 256, 0, stream>>>(logits, targets, fbl, txl, lpb, lpl);
    rna_dp_kernel<<<1, 256, 0, stream>>>(lpb, lpl, fbl, txl, out);
}